// Round 1
// baseline (1082.571 us; speedup 1.0000x reference)
//
#include <hip/hip_runtime.h>
#include <hip/hip_bf16.h>
#include <cstdint>
#include <cstddef>

// Problem constants
#define NP     100352      // 32*56*56 total pixels
#define HW     3136        // 56*56
#define CDIM   384
#define C3     1152        // 3*384
#define NHEAD  12
#define HD     32          // head dim
#define NWIN   2048        // 32 * 8 * 8 windows

typedef __attribute__((ext_vector_type(8))) short bf16x8;
typedef __attribute__((ext_vector_type(4))) float f32x4;

static __device__ __forceinline__ float bf2f(unsigned short u) {
    union { float f; uint32_t i; } v; v.i = ((uint32_t)u) << 16; return v.f;
}
static __device__ __forceinline__ unsigned short f2bf(float f) {
    union { float f; uint32_t i; } v; v.f = f;
    uint32_t r = v.i + 0x7FFFu + ((v.i >> 16) & 1u);   // round-nearest-even
    return (unsigned short)(r >> 16);
}

// ---------------------------------------------------------------------------
// Kernel 1: fp32 -> bf16 weight conversion (vectorized x4)
// ---------------------------------------------------------------------------
__global__ __launch_bounds__(256) void cvt_f32_bf16(
    const float* __restrict__ src, unsigned short* __restrict__ dst, int n4) {
    int i = blockIdx.x * blockDim.x + threadIdx.x;
    if (i < n4) {
        float4 v = ((const float4*)src)[i];
        ushort4 r;
        r.x = f2bf(v.x); r.y = f2bf(v.y); r.z = f2bf(v.z); r.w = f2bf(v.w);
        ((ushort4*)dst)[i] = r;
    }
}

// ---------------------------------------------------------------------------
// Kernel 2: transpose x (B, C, HW) fp32 -> xt (B*HW, C) bf16
// grid (98, 12, 32), block (32, 8)
// ---------------------------------------------------------------------------
__global__ __launch_bounds__(256) void transpose_x(
    const float* __restrict__ x, unsigned short* __restrict__ xt) {
    __shared__ float tile[32][33];
    int b   = blockIdx.z;
    int hw0 = blockIdx.x * 32;
    int c0  = blockIdx.y * 32;
    int tx = threadIdx.x, ty = threadIdx.y;
    const float* xp = x + (size_t)b * CDIM * HW;
#pragma unroll
    for (int i = 0; i < 4; i++) {
        int c = ty + i * 8;
        tile[c][tx] = xp[(size_t)(c0 + c) * HW + hw0 + tx];   // coalesced along hw
    }
    __syncthreads();
    unsigned short* xtp = xt + (size_t)b * HW * CDIM;
#pragma unroll
    for (int i = 0; i < 4; i++) {
        int r = ty + i * 8;                                   // local hw
        xtp[(size_t)(hw0 + r) * CDIM + c0 + tx] = f2bf(tile[tx][r]);  // coalesced along c
    }
}

// ---------------------------------------------------------------------------
// MFMA GEMM main loop (shared by both GEMMs). K = 384 fixed.
// D[m][n] = sum_k A[m][k] * Bt[n][k], 128x128 tile, 256 threads (4 waves 2x2),
// each wave 64x64 via 4x4 grid of 16x16x32 bf16 MFMA.
// LDS rows padded to 40 bf16 (80B): fragment ds_read_b128 conflict-free.
// ---------------------------------------------------------------------------
#define LDSW 40

static __device__ __forceinline__ void gemm_main(
    const unsigned short* __restrict__ A, const unsigned short* __restrict__ Bt,
    int m0, int n0, short* As, short* Bs, f32x4 acc[4][4]) {

    int tid  = threadIdx.x;
    int wv   = tid >> 6;
    int lane = tid & 63;
    int wr = wv >> 1, wc = wv & 1;
    int lrow = lane & 15, lq = lane >> 4;

#pragma unroll
    for (int mi = 0; mi < 4; mi++)
#pragma unroll
        for (int ni = 0; ni < 4; ni++)
            acc[mi][ni] = (f32x4){0.f, 0.f, 0.f, 0.f};

    for (int kt = 0; kt < 12; kt++) {   // K = 384 = 12 * 32
        // stage A-tile and B-tile: 128 rows x 32 bf16 each = 512 x 16B chunks
#pragma unroll
        for (int i = 0; i < 2; i++) {
            int c   = tid + i * 256;
            int row = c >> 2, seg = c & 3;
            uint4 va = *(const uint4*)(A  + (size_t)(m0 + row) * 384 + kt * 32 + seg * 8);
            *(uint4*)(As + row * LDSW + seg * 8) = va;
            uint4 vb = *(const uint4*)(Bt + (size_t)(n0 + row) * 384 + kt * 32 + seg * 8);
            *(uint4*)(Bs + row * LDSW + seg * 8) = vb;
        }
        __syncthreads();

        bf16x8 af[4], bfr[4];
#pragma unroll
        for (int mi = 0; mi < 4; mi++)
            af[mi] = *(const bf16x8*)(As + (wr * 64 + mi * 16 + lrow) * LDSW + lq * 8);
#pragma unroll
        for (int ni = 0; ni < 4; ni++)
            bfr[ni] = *(const bf16x8*)(Bs + (wc * 64 + ni * 16 + lrow) * LDSW + lq * 8);
#pragma unroll
        for (int mi = 0; mi < 4; mi++)
#pragma unroll
            for (int ni = 0; ni < 4; ni++)
                acc[mi][ni] = __builtin_amdgcn_mfma_f32_16x16x32_bf16(
                    af[mi], bfr[ni], acc[mi][ni], 0, 0, 0);
        __syncthreads();
    }
}

// GEMM 1: qkv_t[p][o] = sum_c xt[p][c] * w_qkv[o][c]; output bf16, ldc = 1152
// grid (9, 784): n-tiles x m-tiles
__global__ __launch_bounds__(256) void gemm_qkv(
    const unsigned short* __restrict__ A, const unsigned short* __restrict__ Bt,
    unsigned short* __restrict__ C) {
    __shared__ __align__(16) short As[128 * LDSW];
    __shared__ __align__(16) short Bs[128 * LDSW];
    int m0 = blockIdx.y * 128, n0 = blockIdx.x * 128;
    f32x4 acc[4][4];
    gemm_main(A, Bt, m0, n0, As, Bs, acc);

    int lane = threadIdx.x & 63, wv = threadIdx.x >> 6;
    int wr = wv >> 1, wc = wv & 1;
    int lrow = lane & 15, lq = lane >> 4;
#pragma unroll
    for (int mi = 0; mi < 4; mi++)
#pragma unroll
        for (int ni = 0; ni < 4; ni++)
#pragma unroll
            for (int i = 0; i < 4; i++) {
                int row = m0 + wr * 64 + mi * 16 + lq * 4 + i;   // p
                int col = n0 + wc * 64 + ni * 16 + lrow;         // o
                C[(size_t)row * C3 + col] = f2bf(acc[mi][ni][i]);
            }
}

// GEMM 2: out[b][o][hw] = sum_c w_proj[o][c] * out_t[p][c] + b_proj[o]
// grid (784, 3): n-tiles(p) x m-tiles(o)
__global__ __launch_bounds__(256) void gemm_proj(
    const unsigned short* __restrict__ A, const unsigned short* __restrict__ Bt,
    const float* __restrict__ bias, float* __restrict__ out) {
    __shared__ __align__(16) short As[128 * LDSW];
    __shared__ __align__(16) short Bs[128 * LDSW];
    int m0 = blockIdx.y * 128, n0 = blockIdx.x * 128;
    f32x4 acc[4][4];
    gemm_main(A, Bt, m0, n0, As, Bs, acc);

    int lane = threadIdx.x & 63, wv = threadIdx.x >> 6;
    int wr = wv >> 1, wc = wv & 1;
    int lrow = lane & 15, lq = lane >> 4;
#pragma unroll
    for (int mi = 0; mi < 4; mi++)
#pragma unroll
        for (int ni = 0; ni < 4; ni++) {
            int pcol = n0 + wc * 64 + ni * 16 + lrow;            // global pixel p
            int b = pcol / HW, hw = pcol - b * HW;
#pragma unroll
            for (int i = 0; i < 4; i++) {
                int o = m0 + wr * 64 + mi * 16 + lq * 4 + i;
                out[(size_t)b * CDIM * HW + (size_t)o * HW + hw] = acc[mi][ni][i] + bias[o];
            }
        }
}

// ---------------------------------------------------------------------------
// Kernel 4: window attention. grid (2048, 12), block 64.
// Lane r (< 49) owns query token r of (window, head).
// ---------------------------------------------------------------------------
__global__ __launch_bounds__(64) void attn_win(
    const unsigned short* __restrict__ qkv, const float* __restrict__ btab,
    unsigned short* __restrict__ outt) {
    int w = blockIdx.x, h = blockIdx.y;
    int lane = threadIdx.x;
    int b = w >> 6, wy = (w >> 3) & 7, wx = w & 7;
    int pbase = b * HW + wy * 7 * 56 + wx * 7;

    __shared__ float Q[49][32];
    __shared__ float Kt[49][32];
    __shared__ float V[49][32];
    __shared__ float S[49][49];

    const float scale = 0.17677669529663689f;  // 1/sqrt(32)

    // load q,k,v: 3 * 49 tokens * 4 chunks of 8 bf16
    for (int c = lane; c < 588; c += 64) {
        int s = c / 196, cc = c - s * 196;
        int tok = cc >> 2, seg = cc & 3;
        int p = pbase + (tok / 7) * 56 + (tok % 7);
        const unsigned short* src = qkv + (size_t)p * C3 + s * CDIM + h * HD + seg * 8;
        uint4 v = *(const uint4*)src;
        const unsigned short* u = (const unsigned short*)&v;
        float sc = (s == 0) ? scale : 1.0f;
        float* dst = (s == 0 ? &Q[0][0] : (s == 1 ? &Kt[0][0] : &V[0][0])) + tok * 32 + seg * 8;
        float4 lo, hi;
        lo.x = bf2f(u[0]) * sc; lo.y = bf2f(u[1]) * sc;
        lo.z = bf2f(u[2]) * sc; lo.w = bf2f(u[3]) * sc;
        hi.x = bf2f(u[4]) * sc; hi.y = bf2f(u[5]) * sc;
        hi.z = bf2f(u[6]) * sc; hi.w = bf2f(u[7]) * sc;
        *(float4*)dst = lo;
        *(float4*)(dst + 4) = hi;
    }
    __syncthreads();

    if (lane < 49) {
        int ri = lane / 7, rj = lane - ri * 7;
        float qr[32];
#pragma unroll
        for (int d = 0; d < 32; d++) qr[d] = Q[lane][d];

        float mx = -1e30f;
        for (int mi = 0; mi < 7; mi++)
            for (int mj = 0; mj < 7; mj++) {
                int m = mi * 7 + mj;
                float a = 0.f;
#pragma unroll
                for (int d = 0; d < 32; d++) a += qr[d] * Kt[m][d];
                a += btab[((ri - mi + 6) * 13 + (rj - mj + 6)) * NHEAD + h];
                S[lane][m] = a;
                mx = fmaxf(mx, a);
            }
        float sum = 0.f;
        for (int m = 0; m < 49; m++) {
            float e = __expf(S[lane][m] - mx);
            S[lane][m] = e;
            sum += e;
        }
        float inv = 1.0f / sum;

        float o[32];
#pragma unroll
        for (int d = 0; d < 32; d++) o[d] = 0.f;
        for (int m = 0; m < 49; m++) {
            float pm = S[lane][m];
#pragma unroll
            for (int d = 0; d < 32; d++) o[d] += pm * V[m][d];
        }

        int p = pbase + ri * 56 + rj;
        unsigned short ov[32];
#pragma unroll
        for (int d = 0; d < 32; d++) ov[d] = f2bf(o[d] * inv);
        unsigned short* dst = outt + (size_t)p * CDIM + h * HD;
#pragma unroll
        for (int s4 = 0; s4 < 4; s4++)
            *(uint4*)(dst + s4 * 8) = *(const uint4*)(ov + s4 * 8);
    }
}

// ---------------------------------------------------------------------------
// Launch
// ---------------------------------------------------------------------------
extern "C" void kernel_launch(void* const* d_in, const int* in_sizes, int n_in,
                              void* d_out, int out_size, void* d_ws, size_t ws_size,
                              hipStream_t stream) {
    const float* x      = (const float*)d_in[0];
    const float* w_qkv  = (const float*)d_in[1];
    const float* btab   = (const float*)d_in[2];
    const float* w_proj = (const float*)d_in[3];
    const float* b_proj = (const float*)d_in[4];
    float* out = (float*)d_out;

    // workspace layout (bytes)
    char* ws = (char*)d_ws;
    const size_t off_xt   = 0;                         // 100352*384*2 = 77,070,336 (reused as out_t)
    const size_t off_qkv  = 77070336;                  // 100352*1152*2 = 231,211,008
    const size_t off_wq   = off_qkv + 231211008;       // 884,736
    const size_t off_wp   = off_wq + 884736;           // 294,912
    unsigned short* xt   = (unsigned short*)(ws + off_xt);
    unsigned short* qkvt = (unsigned short*)(ws + off_qkv);
    unsigned short* wqb  = (unsigned short*)(ws + off_wq);
    unsigned short* wpb  = (unsigned short*)(ws + off_wp);
    unsigned short* outt = xt;   // alias: xt dead after gemm_qkv

    cvt_f32_bf16<<<(C3 * CDIM / 4 + 255) / 256, 256, 0, stream>>>(w_qkv, wqb, C3 * CDIM / 4);
    cvt_f32_bf16<<<(CDIM * CDIM / 4 + 255) / 256, 256, 0, stream>>>(w_proj, wpb, CDIM * CDIM / 4);
    transpose_x<<<dim3(98, 12, 32), dim3(32, 8), 0, stream>>>(x, xt);
    gemm_qkv<<<dim3(9, 784), 256, 0, stream>>>(xt, wqb, qkvt);
    attn_win<<<dim3(NWIN, NHEAD), 64, 0, stream>>>(qkvt, btab, outt);
    gemm_proj<<<dim3(784, 3), 256, 0, stream>>>(wpb, outt, b_proj, out);
}

// Round 2
// 698.976 us; speedup vs baseline: 1.5488x; 1.5488x over previous
//
#include <hip/hip_runtime.h>
#include <hip/hip_bf16.h>
#include <cstdint>
#include <cstddef>

// Problem constants
#define NP     100352      // 32*56*56 total pixels
#define HW     3136        // 56*56
#define CDIM   384
#define C3     1152        // 3*384
#define NHEAD  12
#define HD     32          // head dim
#define NWIN   2048        // 32 * 8 * 8 windows

typedef __attribute__((ext_vector_type(8))) short bf16x8;
typedef __attribute__((ext_vector_type(4))) float f32x4;

static __device__ __forceinline__ float bf2f(unsigned short u) {
    union { float f; uint32_t i; } v; v.i = ((uint32_t)u) << 16; return v.f;
}
static __device__ __forceinline__ unsigned short f2bf(float f) {
    union { float f; uint32_t i; } v; v.f = f;
    uint32_t r = v.i + 0x7FFFu + ((v.i >> 16) & 1u);   // round-nearest-even
    return (unsigned short)(r >> 16);
}

// async global->LDS, 16B per lane; LDS dest = uniform base + lane*16
static __device__ __forceinline__ void gld_lds16(const void* g, void* l) {
    __builtin_amdgcn_global_load_lds(
        (const __attribute__((address_space(1))) void*)g,
        (__attribute__((address_space(3))) void*)l, 16, 0, 0);
}

// ---------------------------------------------------------------------------
// Kernel 1: fp32 -> bf16 weight conversion (vectorized x4)
// ---------------------------------------------------------------------------
__global__ __launch_bounds__(256) void cvt_f32_bf16(
    const float* __restrict__ src, unsigned short* __restrict__ dst, int n4) {
    int i = blockIdx.x * blockDim.x + threadIdx.x;
    if (i < n4) {
        float4 v = ((const float4*)src)[i];
        ushort4 r;
        r.x = f2bf(v.x); r.y = f2bf(v.y); r.z = f2bf(v.z); r.w = f2bf(v.w);
        ((ushort4*)dst)[i] = r;
    }
}

// ---------------------------------------------------------------------------
// Kernel 2: transpose x (B, C, HW) fp32 -> xt (B*HW, C) bf16
// grid (98, 12, 32), block (32, 8)
// ---------------------------------------------------------------------------
__global__ __launch_bounds__(256) void transpose_x(
    const float* __restrict__ x, unsigned short* __restrict__ xt) {
    __shared__ float tile[32][33];
    int b   = blockIdx.z;
    int hw0 = blockIdx.x * 32;
    int c0  = blockIdx.y * 32;
    int tx = threadIdx.x, ty = threadIdx.y;
    const float* xp = x + (size_t)b * CDIM * HW;
#pragma unroll
    for (int i = 0; i < 4; i++) {
        int c = ty + i * 8;
        tile[c][tx] = xp[(size_t)(c0 + c) * HW + hw0 + tx];   // coalesced along hw
    }
    __syncthreads();
    unsigned short* xtp = xt + (size_t)b * HW * CDIM;
#pragma unroll
    for (int i = 0; i < 4; i++) {
        int r = ty + i * 8;                                   // local hw
        xtp[(size_t)(hw0 + r) * CDIM + c0 + tx] = f2bf(tile[tx][r]);  // coalesced along c
    }
}

// ---------------------------------------------------------------------------
// MFMA GEMM main loop (m97 structure). K = 384 fixed.
// D[m][n] = sum_k A[m][k] * Bt[n][k], 128x128 tile, 256 threads (4 waves 2x2),
// each wave 64x64 via 4x4 grid of 16x16x32 bf16 MFMA.
// Staging: global_load_lds width=16, unpadded LDS rows (32 bf16 = 64 B).
// ---------------------------------------------------------------------------
static __device__ __forceinline__ void gemm_main(
    const unsigned short* __restrict__ A, const unsigned short* __restrict__ Bt,
    int m0, int n0, unsigned short* As, unsigned short* Bs, f32x4 acc[4][4]) {

    int tid  = threadIdx.x;
    int wv   = tid >> 6;
    int lane = tid & 63;
    int wr = wv >> 1, wc = wv & 1;
    int lrow = lane & 15, lq = lane >> 4;

#pragma unroll
    for (int mi = 0; mi < 4; mi++)
#pragma unroll
        for (int ni = 0; ni < 4; ni++)
            acc[mi][ni] = (f32x4){0.f, 0.f, 0.f, 0.f};

    for (int kt = 0; kt < 12; kt++) {   // K = 384 = 12 * 32
        // stage A-tile and B-tile: each 128 rows x 32 bf16 = 8192 B = 8 chunks
        // of 1024 B; wave w stages chunks {2w, 2w+1} of each.
#pragma unroll
        for (int i = 0; i < 2; i++) {
            int ch  = wv * 2 + i;
            int row = ch * 16 + (lane >> 2);
            int seg = lane & 3;
            gld_lds16(A  + (size_t)(m0 + row) * 384 + kt * 32 + seg * 8, As + ch * 512);
            gld_lds16(Bt + (size_t)(n0 + row) * 384 + kt * 32 + seg * 8, Bs + ch * 512);
        }
        __syncthreads();

        bf16x8 af[4], bfr[4];
#pragma unroll
        for (int mi = 0; mi < 4; mi++)
            af[mi] = *(const bf16x8*)(As + (wr * 64 + mi * 16 + lrow) * 32 + lq * 8);
#pragma unroll
        for (int ni = 0; ni < 4; ni++)
            bfr[ni] = *(const bf16x8*)(Bs + (wc * 64 + ni * 16 + lrow) * 32 + lq * 8);
#pragma unroll
        for (int mi = 0; mi < 4; mi++)
#pragma unroll
            for (int ni = 0; ni < 4; ni++)
                acc[mi][ni] = __builtin_amdgcn_mfma_f32_16x16x32_bf16(
                    af[mi], bfr[ni], acc[mi][ni], 0, 0, 0);
        __syncthreads();
    }
}

// GEMM 1: qkv_t[p][o] = sum_c xt[p][c] * w_qkv[o][c]; output bf16, ldc = 1152
// grid (9, 784): n-tiles x m-tiles
__global__ __launch_bounds__(256) void gemm_qkv(
    const unsigned short* __restrict__ A, const unsigned short* __restrict__ Bt,
    unsigned short* __restrict__ C) {
    __shared__ __align__(16) unsigned short As[128 * 32];
    __shared__ __align__(16) unsigned short Bs[128 * 32];
    int m0 = blockIdx.y * 128, n0 = blockIdx.x * 128;
    f32x4 acc[4][4];
    gemm_main(A, Bt, m0, n0, As, Bs, acc);

    int lane = threadIdx.x & 63, wv = threadIdx.x >> 6;
    int wr = wv >> 1, wc = wv & 1;
    int lrow = lane & 15, lq = lane >> 4;
#pragma unroll
    for (int mi = 0; mi < 4; mi++)
#pragma unroll
        for (int ni = 0; ni < 4; ni++)
#pragma unroll
            for (int i = 0; i < 4; i++) {
                int row = m0 + wr * 64 + mi * 16 + lq * 4 + i;   // p
                int col = n0 + wc * 64 + ni * 16 + lrow;         // o
                C[(size_t)row * C3 + col] = f2bf(acc[mi][ni][i]);
            }
}

// GEMM 2: out[b][o][hw] = sum_c w_proj[o][c] * out_t[p][c] + b_proj[o]
// grid (784, 3): n-tiles(p) x m-tiles(o)
__global__ __launch_bounds__(256) void gemm_proj(
    const unsigned short* __restrict__ A, const unsigned short* __restrict__ Bt,
    const float* __restrict__ bias, float* __restrict__ out) {
    __shared__ __align__(16) unsigned short As[128 * 32];
    __shared__ __align__(16) unsigned short Bs[128 * 32];
    int m0 = blockIdx.y * 128, n0 = blockIdx.x * 128;
    f32x4 acc[4][4];
    gemm_main(A, Bt, m0, n0, As, Bs, acc);

    int lane = threadIdx.x & 63, wv = threadIdx.x >> 6;
    int wr = wv >> 1, wc = wv & 1;
    int lrow = lane & 15, lq = lane >> 4;
#pragma unroll
    for (int mi = 0; mi < 4; mi++)
#pragma unroll
        for (int ni = 0; ni < 4; ni++) {
            int pcol = n0 + wc * 64 + ni * 16 + lrow;            // global pixel p
            int b = pcol / HW, hw = pcol - b * HW;
#pragma unroll
            for (int i = 0; i < 4; i++) {
                int o = m0 + wr * 64 + mi * 16 + lq * 4 + i;
                out[(size_t)b * CDIM * HW + (size_t)o * HW + hw] = acc[mi][ni][i] + bias[o];
            }
        }
}

// ---------------------------------------------------------------------------
// Kernel 4: window attention. grid (2048, 12), block 64 (1 wave).
// Lane r (< 49) owns query token r. K,V fp32 in LDS (12.5 KB); S,Q,O in regs.
// ---------------------------------------------------------------------------
__global__ __launch_bounds__(64) void attn_win(
    const unsigned short* __restrict__ qkv, const float* __restrict__ btab,
    unsigned short* __restrict__ outt) {
    int w = blockIdx.x, h = blockIdx.y;
    int lane = threadIdx.x;
    int b = w >> 6, wy = (w >> 3) & 7, wx = w & 7;
    int pbase = b * HW + wy * 7 * 56 + wx * 7;

    __shared__ float Kt[49][32];
    __shared__ float V[49][32];

    const float scale = 0.17677669529663689f;  // 1/sqrt(32)

    // cooperative K/V load: 98 rows * 4 segs of 8 bf16 = 392 chunks
    for (int c = lane; c < 392; c += 64) {
        int row2 = c >> 2, seg = c & 3;
        int isv = row2 >= 49;
        int tok = row2 - (isv ? 49 : 0);
        int p = pbase + (tok / 7) * 56 + (tok % 7);
        const unsigned short* src = qkv + (size_t)p * C3 + (isv ? 2 : 1) * CDIM + h * HD + seg * 8;
        uint4 v = *(const uint4*)src;
        const unsigned short* u = (const unsigned short*)&v;
        float* dst = (isv ? &V[0][0] : &Kt[0][0]) + tok * 32 + seg * 8;
        float4 lo, hi;
        lo.x = bf2f(u[0]); lo.y = bf2f(u[1]); lo.z = bf2f(u[2]); lo.w = bf2f(u[3]);
        hi.x = bf2f(u[4]); hi.y = bf2f(u[5]); hi.z = bf2f(u[6]); hi.w = bf2f(u[7]);
        *(float4*)dst = lo;
        *(float4*)(dst + 4) = hi;
    }

    // lane r loads its own q row (scaled) straight from global
    float4 q4[8];
    int ri = 0, rj = 0;
    if (lane < 49) {
        ri = lane / 7; rj = lane - ri * 7;
        int p = pbase + ri * 56 + rj;
        const unsigned short* src = qkv + (size_t)p * C3 + h * HD;
#pragma unroll
        for (int seg = 0; seg < 4; seg++) {
            uint4 v = *(const uint4*)(src + seg * 8);
            const unsigned short* u = (const unsigned short*)&v;
            float4 a, bq;
            a.x = bf2f(u[0]) * scale; a.y = bf2f(u[1]) * scale;
            a.z = bf2f(u[2]) * scale; a.w = bf2f(u[3]) * scale;
            bq.x = bf2f(u[4]) * scale; bq.y = bf2f(u[5]) * scale;
            bq.z = bf2f(u[6]) * scale; bq.w = bf2f(u[7]) * scale;
            q4[seg * 2] = a; q4[seg * 2 + 1] = bq;
        }
    }
    __syncthreads();

    if (lane < 49) {
        float S[49];
        float mx = -1e30f;
#pragma unroll
        for (int m = 0; m < 49; m++) {
            int mi = m / 7, mj = m - mi * 7;
            const float4* kr = (const float4*)(&Kt[m][0]);
            float4 a4 = {0.f, 0.f, 0.f, 0.f};
#pragma unroll
            for (int t = 0; t < 8; t++) {
                float4 kv = kr[t];
                a4.x += q4[t].x * kv.x; a4.y += q4[t].y * kv.y;
                a4.z += q4[t].z * kv.z; a4.w += q4[t].w * kv.w;
            }
            float a = (a4.x + a4.y) + (a4.z + a4.w);
            a += btab[((ri - mi + 6) * 13 + (rj - mj + 6)) * NHEAD + h];
            S[m] = a;
            mx = fmaxf(mx, a);
        }
        float sum = 0.f;
#pragma unroll
        for (int m = 0; m < 49; m++) {
            float e = __expf(S[m] - mx);
            S[m] = e;
            sum += e;
        }
        float inv = 1.0f / sum;

        float4 o4[8];
#pragma unroll
        for (int t = 0; t < 8; t++) o4[t] = (float4){0.f, 0.f, 0.f, 0.f};
#pragma unroll
        for (int m = 0; m < 49; m++) {
            float pm = S[m];
            const float4* vr = (const float4*)(&V[m][0]);
#pragma unroll
            for (int t = 0; t < 8; t++) {
                float4 vv = vr[t];
                o4[t].x += pm * vv.x; o4[t].y += pm * vv.y;
                o4[t].z += pm * vv.z; o4[t].w += pm * vv.w;
            }
        }

        int p = pbase + ri * 56 + rj;
        unsigned short ov[32];
#pragma unroll
        for (int t = 0; t < 8; t++) {
            ov[t * 4 + 0] = f2bf(o4[t].x * inv);
            ov[t * 4 + 1] = f2bf(o4[t].y * inv);
            ov[t * 4 + 2] = f2bf(o4[t].z * inv);
            ov[t * 4 + 3] = f2bf(o4[t].w * inv);
        }
        unsigned short* dst = outt + (size_t)p * CDIM + h * HD;
#pragma unroll
        for (int s4 = 0; s4 < 4; s4++)
            *(uint4*)(dst + s4 * 8) = *(const uint4*)(ov + s4 * 8);
    }
}

// ---------------------------------------------------------------------------
// Launch
// ---------------------------------------------------------------------------
extern "C" void kernel_launch(void* const* d_in, const int* in_sizes, int n_in,
                              void* d_out, int out_size, void* d_ws, size_t ws_size,
                              hipStream_t stream) {
    const float* x      = (const float*)d_in[0];
    const float* w_qkv  = (const float*)d_in[1];
    const float* btab   = (const float*)d_in[2];
    const float* w_proj = (const float*)d_in[3];
    const float* b_proj = (const float*)d_in[4];
    float* out = (float*)d_out;

    // workspace layout (bytes)
    char* ws = (char*)d_ws;
    const size_t off_xt   = 0;                         // 100352*384*2 = 77,070,336 (reused as out_t)
    const size_t off_qkv  = 77070336;                  // 100352*1152*2 = 231,211,008
    const size_t off_wq   = off_qkv + 231211008;       // 884,736
    const size_t off_wp   = off_wq + 884736;           // 294,912
    unsigned short* xt   = (unsigned short*)(ws + off_xt);
    unsigned short* qkvt = (unsigned short*)(ws + off_qkv);
    unsigned short* wqb  = (unsigned short*)(ws + off_wq);
    unsigned short* wpb  = (unsigned short*)(ws + off_wp);
    unsigned short* outt = xt;   // alias: xt dead after gemm_qkv

    cvt_f32_bf16<<<(C3 * CDIM / 4 + 255) / 256, 256, 0, stream>>>(w_qkv, wqb, C3 * CDIM / 4);
    cvt_f32_bf16<<<(CDIM * CDIM / 4 + 255) / 256, 256, 0, stream>>>(w_proj, wpb, CDIM * CDIM / 4);
    transpose_x<<<dim3(98, 12, 32), dim3(32, 8), 0, stream>>>(x, xt);
    gemm_qkv<<<dim3(9, 784), 256, 0, stream>>>(xt, wqb, qkvt);
    attn_win<<<dim3(NWIN, NHEAD), 64, 0, stream>>>(qkvt, btab, outt);
    gemm_proj<<<dim3(784, 3), 256, 0, stream>>>(wpb, outt, b_proj, out);
}

// Round 3
// 605.340 us; speedup vs baseline: 1.7884x; 1.1547x over previous
//
#include <hip/hip_runtime.h>
#include <hip/hip_bf16.h>
#include <cstdint>
#include <cstddef>

// Problem constants
#define NP     100352      // 32*56*56 total pixels
#define HW     3136        // 56*56
#define CDIM   384
#define C3     1152        // 3*384
#define NHEAD  12
#define HD     32          // head dim
#define NWIN   2048        // 32 * 8 * 8 windows

typedef __attribute__((ext_vector_type(8))) short bf16x8;
typedef __attribute__((ext_vector_type(4))) float f32x4;

static __device__ __forceinline__ float bf2f(unsigned short u) {
    union { float f; uint32_t i; } v; v.i = ((uint32_t)u) << 16; return v.f;
}
static __device__ __forceinline__ unsigned short f2bf(float f) {
    union { float f; uint32_t i; } v; v.f = f;
    uint32_t r = v.i + 0x7FFFu + ((v.i >> 16) & 1u);   // round-nearest-even
    return (unsigned short)(r >> 16);
}
// pack two f32 -> bf16 pair (round-half-up; lo half = a)
static __device__ __forceinline__ uint32_t pk2(float a, float b) {
    union { float f; uint32_t u; } x, y; x.f = a; y.f = b;
    return ((x.u + 0x8000u) >> 16) | ((y.u + 0x8000u) & 0xffff0000u);
}

// async global->LDS, 16B per lane; LDS dest = uniform base + lane*16
static __device__ __forceinline__ void gld_lds16(const void* g, void* l) {
    __builtin_amdgcn_global_load_lds(
        (const __attribute__((address_space(1))) void*)g,
        (__attribute__((address_space(3))) void*)l, 16, 0, 0);
}

// ---------------------------------------------------------------------------
// Kernel 1: fp32 -> bf16 weight conversion (vectorized x4)
// ---------------------------------------------------------------------------
__global__ __launch_bounds__(256) void cvt_f32_bf16(
    const float* __restrict__ src, unsigned short* __restrict__ dst, int n4) {
    int i = blockIdx.x * blockDim.x + threadIdx.x;
    if (i < n4) {
        float4 v = ((const float4*)src)[i];
        ushort4 r;
        r.x = f2bf(v.x); r.y = f2bf(v.y); r.z = f2bf(v.z); r.w = f2bf(v.w);
        ((ushort4*)dst)[i] = r;
    }
}

// ---------------------------------------------------------------------------
// Kernel 1b: precompute bias_t[h][query][key] fp32 (64x64 padded, / scale,
// -1e30 on pads so softmax masking is free). 12*64*64 = 49152 elems.
// ---------------------------------------------------------------------------
__global__ __launch_bounds__(256) void bias_pre(
    const float* __restrict__ btab, float* __restrict__ bias_t) {
    int idx = blockIdx.x * 256 + threadIdx.x;
    int h = idx >> 12, query = (idx >> 6) & 63, key = idx & 63;
    float v = -1e30f;
    if (query < 49 && key < 49) {
        int ri = query / 7, rj = query % 7, mi = key / 7, mj = key % 7;
        v = btab[((ri - mi + 6) * 13 + (rj - mj + 6)) * NHEAD + h] * 5.656854249492381f;
    }
    bias_t[idx] = v;
}

// ---------------------------------------------------------------------------
// Kernel 2: transpose x (B, C, HW) fp32 -> xt (B*HW, C) bf16
// grid (98, 12, 32), block (32, 8)
// ---------------------------------------------------------------------------
__global__ __launch_bounds__(256) void transpose_x(
    const float* __restrict__ x, unsigned short* __restrict__ xt) {
    __shared__ float tile[32][33];
    int b   = blockIdx.z;
    int hw0 = blockIdx.x * 32;
    int c0  = blockIdx.y * 32;
    int tx = threadIdx.x, ty = threadIdx.y;
    const float* xp = x + (size_t)b * CDIM * HW;
#pragma unroll
    for (int i = 0; i < 4; i++) {
        int c = ty + i * 8;
        tile[c][tx] = xp[(size_t)(c0 + c) * HW + hw0 + tx];   // coalesced along hw
    }
    __syncthreads();
    unsigned short* xtp = xt + (size_t)b * HW * CDIM;
#pragma unroll
    for (int i = 0; i < 4; i++) {
        int r = ty + i * 8;                                   // local hw
        xtp[(size_t)(hw0 + r) * CDIM + c0 + tx] = f2bf(tile[tx][r]);  // coalesced along c
    }
}

// ---------------------------------------------------------------------------
// MFMA GEMM main loop (m97 structure). K = 384 fixed.
// ---------------------------------------------------------------------------
static __device__ __forceinline__ void gemm_main(
    const unsigned short* __restrict__ A, const unsigned short* __restrict__ Bt,
    int m0, int n0, unsigned short* As, unsigned short* Bs, f32x4 acc[4][4]) {

    int tid  = threadIdx.x;
    int wv   = tid >> 6;
    int lane = tid & 63;
    int wr = wv >> 1, wc = wv & 1;
    int lrow = lane & 15, lq = lane >> 4;

#pragma unroll
    for (int mi = 0; mi < 4; mi++)
#pragma unroll
        for (int ni = 0; ni < 4; ni++)
            acc[mi][ni] = (f32x4){0.f, 0.f, 0.f, 0.f};

    for (int kt = 0; kt < 12; kt++) {   // K = 384 = 12 * 32
#pragma unroll
        for (int i = 0; i < 2; i++) {
            int ch  = wv * 2 + i;
            int row = ch * 16 + (lane >> 2);
            int seg = lane & 3;
            gld_lds16(A  + (size_t)(m0 + row) * 384 + kt * 32 + seg * 8, As + ch * 512);
            gld_lds16(Bt + (size_t)(n0 + row) * 384 + kt * 32 + seg * 8, Bs + ch * 512);
        }
        __syncthreads();

        bf16x8 af[4], bfr[4];
#pragma unroll
        for (int mi = 0; mi < 4; mi++)
            af[mi] = *(const bf16x8*)(As + (wr * 64 + mi * 16 + lrow) * 32 + lq * 8);
#pragma unroll
        for (int ni = 0; ni < 4; ni++)
            bfr[ni] = *(const bf16x8*)(Bs + (wc * 64 + ni * 16 + lrow) * 32 + lq * 8);
#pragma unroll
        for (int mi = 0; mi < 4; mi++)
#pragma unroll
            for (int ni = 0; ni < 4; ni++)
                acc[mi][ni] = __builtin_amdgcn_mfma_f32_16x16x32_bf16(
                    af[mi], bfr[ni], acc[mi][ni], 0, 0, 0);
        __syncthreads();
    }
}

// GEMM 1: qkv_t[p][o] = sum_c xt[p][c] * w_qkv[o][c]; output bf16, ldc = 1152
__global__ __launch_bounds__(256) void gemm_qkv(
    const unsigned short* __restrict__ A, const unsigned short* __restrict__ Bt,
    unsigned short* __restrict__ C) {
    __shared__ __align__(16) unsigned short As[128 * 32];
    __shared__ __align__(16) unsigned short Bs[128 * 32];
    int m0 = blockIdx.y * 128, n0 = blockIdx.x * 128;
    f32x4 acc[4][4];
    gemm_main(A, Bt, m0, n0, As, Bs, acc);

    int lane = threadIdx.x & 63, wv = threadIdx.x >> 6;
    int wr = wv >> 1, wc = wv & 1;
    int lrow = lane & 15, lq = lane >> 4;
#pragma unroll
    for (int mi = 0; mi < 4; mi++)
#pragma unroll
        for (int ni = 0; ni < 4; ni++)
#pragma unroll
            for (int i = 0; i < 4; i++) {
                int row = m0 + wr * 64 + mi * 16 + lq * 4 + i;   // p
                int col = n0 + wc * 64 + ni * 16 + lrow;         // o
                C[(size_t)row * C3 + col] = f2bf(acc[mi][ni][i]);
            }
}

// GEMM 2: out[b][o][hw] = sum_c w_proj[o][c] * out_t[p][c] + b_proj[o]
__global__ __launch_bounds__(256) void gemm_proj(
    const unsigned short* __restrict__ A, const unsigned short* __restrict__ Bt,
    const float* __restrict__ bias, float* __restrict__ out) {
    __shared__ __align__(16) unsigned short As[128 * 32];
    __shared__ __align__(16) unsigned short Bs[128 * 32];
    int m0 = blockIdx.y * 128, n0 = blockIdx.x * 128;
    f32x4 acc[4][4];
    gemm_main(A, Bt, m0, n0, As, Bs, acc);

    int lane = threadIdx.x & 63, wv = threadIdx.x >> 6;
    int wr = wv >> 1, wc = wv & 1;
    int lrow = lane & 15, lq = lane >> 4;
#pragma unroll
    for (int mi = 0; mi < 4; mi++)
#pragma unroll
        for (int ni = 0; ni < 4; ni++) {
            int pcol = n0 + wc * 64 + ni * 16 + lrow;            // global pixel p
            int b = pcol / HW, hw = pcol - b * HW;
#pragma unroll
            for (int i = 0; i < 4; i++) {
                int o = m0 + wr * 64 + mi * 16 + lq * 4 + i;
                out[(size_t)b * CDIM * HW + (size_t)o * HW + hw] = acc[mi][ni][i] + bias[o];
            }
        }
}

// ---------------------------------------------------------------------------
// Kernel 4: MFMA window attention. grid (2048, 12), block 64 (1 wave).
// Computes S^T = K.Q^T (A=K, B=Q frags read DIRECTLY from qkvt: natural
// layout), C-init = bias_t[h][query][key] (bias/scale, -1e30 pads -> free
// masking). Softmax over keys = per-lane 16-reg reduce + shfl_xor(16,32).
// P[query][key] -> LDS (rows padded to 72 elems, 16B-aligned b128 reads).
// O^T = V^T.P^T via MFMA; V^T built by b16 scatter at staging.
// ---------------------------------------------------------------------------
__global__ __launch_bounds__(64, 3) void attn_mfma(
    const unsigned short* __restrict__ qkv, const float* __restrict__ bias_t,
    unsigned short* __restrict__ outt) {
    int w = blockIdx.x, h = blockIdx.y;
    int lane = threadIdx.x;
    int q = lane >> 4, c15 = lane & 15;
    int b = w >> 6, wy = (w >> 3) & 7, wx = w & 7;
    int pbase = b * HW + wy * 7 * 56 + wx * 7;

    __shared__ __align__(16) unsigned short sVT[32 * 72];  // V^T[d][key]
    __shared__ __align__(16) unsigned short sP[64 * 72];   // P[query][key]

    // token -> pixel for tile index t (used by Q/K frags and O stores)
    int p_t[4]; int valid[4];
#pragma unroll
    for (int t = 0; t < 4; t++) {
        int tok = c15 + 16 * t;
        valid[t] = tok < 49;
        int tc = valid[t] ? tok : 48;             // clamp (finite garbage; bias masks)
        p_t[t] = pbase + (tc / 7) * 56 + (tc % 7);
    }

    // zero V^T (pad key columns must be finite)
    {
        uint4* z = (uint4*)sVT;                   // 32*72*2/16 = 288 chunks
#pragma unroll
        for (int i = 0; i < 5; i++) {
            int idx = lane + 64 * i;
            if (idx < 288) z[idx] = (uint4){0u, 0u, 0u, 0u};
        }
    }

    // K,Q fragments straight from global: frag[row=lane&15][k=q*8+j]
    bf16x8 kf[4], qf[4];
#pragma unroll
    for (int t = 0; t < 4; t++) {
        const unsigned short* base = qkv + (size_t)p_t[t] * C3 + h * HD + q * 8;
        qf[t] = *(const bf16x8*)(base);           // Q at o-offset 0
        kf[t] = *(const bf16x8*)(base + CDIM);    // K at o-offset 384
    }

    // stage V transposed: sVT[d][tok]
#pragma unroll
    for (int it = 0; it < 4; it++) {
        int c = lane + 64 * it;
        if (c < 196) {
            int tok = c >> 2, s = c & 3;
            int p = pbase + (tok / 7) * 56 + (tok % 7);
            uint4 v = *(const uint4*)(qkv + (size_t)p * C3 + 2 * CDIM + h * HD + s * 8);
            const unsigned short* vp = (const unsigned short*)&v;
#pragma unroll
            for (int i = 0; i < 8; i++)
                sVT[(8 * s + i) * 72 + tok] = vp[i];
        }
    }

    // S^T accumulators, C-init with bias_t[h][query][key] (float4-aligned)
    f32x4 acc[4][4];
    const float* bp = bias_t + (size_t)h * 64 * 64;
#pragma unroll
    for (int nt = 0; nt < 4; nt++) {
        const float* bq = bp + (c15 + 16 * nt) * 64 + 4 * q;
#pragma unroll
        for (int mt = 0; mt < 4; mt++)
            acc[mt][nt] = *(const f32x4*)(bq + 16 * mt);
    }

    // QK^T (K=32 in one MFMA step): acc[key-tile][query-tile]
#pragma unroll
    for (int mt = 0; mt < 4; mt++)
#pragma unroll
        for (int nt = 0; nt < 4; nt++)
            acc[mt][nt] = __builtin_amdgcn_mfma_f32_16x16x32_bf16(
                kf[mt], qf[nt], acc[mt][nt], 0, 0, 0);

    // softmax over keys, per query column; scale folded into exp2 constant:
    // S_ref = scale*(QK + bias/scale)  =>  e = exp2((acc - max) * scale*log2e)
    const float KSC = 0.25503472f;                // 2^-2.5 * log2(e)
#pragma unroll
    for (int nt = 0; nt < 4; nt++) {
        float mx = acc[0][nt][0];
#pragma unroll
        for (int mt = 0; mt < 4; mt++)
#pragma unroll
            for (int r = 0; r < 4; r++) mx = fmaxf(mx, acc[mt][nt][r]);
        mx = fmaxf(mx, __shfl_xor(mx, 16));
        mx = fmaxf(mx, __shfl_xor(mx, 32));
        float sum = 0.f;
#pragma unroll
        for (int mt = 0; mt < 4; mt++)
#pragma unroll
            for (int r = 0; r < 4; r++) {
                float e = exp2f((acc[mt][nt][r] - mx) * KSC);
                acc[mt][nt][r] = e;
                sum += e;
            }
        sum += __shfl_xor(sum, 16);
        sum += __shfl_xor(sum, 32);
        float inv = 1.0f / sum;
        // pack 4 consecutive keys -> ds_write_b64 into P[query][key]
#pragma unroll
        for (int mt = 0; mt < 4; mt++) {
            uint32_t u01 = pk2(acc[mt][nt][0] * inv, acc[mt][nt][1] * inv);
            uint32_t u23 = pk2(acc[mt][nt][2] * inv, acc[mt][nt][3] * inv);
            *(uint2*)(sP + (c15 + 16 * nt) * 72 + 4 * q + 16 * mt) =
                make_uint2(u01, u23);
        }
    }

    // PV: O^T[d][query] = sum_key V^T[d][key] * P[query][key]
    bf16x8 pf[4][2], vf[2][2];
#pragma unroll
    for (int nt = 0; nt < 4; nt++)
#pragma unroll
        for (int ks = 0; ks < 2; ks++)
            pf[nt][ks] = *(const bf16x8*)(sP + (c15 + 16 * nt) * 72 + q * 8 + 32 * ks);
#pragma unroll
    for (int mt = 0; mt < 2; mt++)
#pragma unroll
        for (int ks = 0; ks < 2; ks++)
            vf[mt][ks] = *(const bf16x8*)(sVT + (c15 + 16 * mt) * 72 + q * 8 + 32 * ks);

    f32x4 oacc[2][4];
#pragma unroll
    for (int mt = 0; mt < 2; mt++)
#pragma unroll
        for (int nt = 0; nt < 4; nt++)
            oacc[mt][nt] = (f32x4){0.f, 0.f, 0.f, 0.f};
#pragma unroll
    for (int ks = 0; ks < 2; ks++)
#pragma unroll
        for (int mt = 0; mt < 2; mt++)
#pragma unroll
            for (int nt = 0; nt < 4; nt++)
                oacc[mt][nt] = __builtin_amdgcn_mfma_f32_16x16x32_bf16(
                    vf[mt][ks], pf[nt][ks], oacc[mt][nt], 0, 0, 0);

    // store: lane's query col = c15+16nt (valid<49), rows d = 4q+r+16mt
#pragma unroll
    for (int nt = 0; nt < 4; nt++) {
        if (valid[nt]) {
            unsigned short* dst = outt + (size_t)p_t[nt] * CDIM + h * HD + 4 * q;
#pragma unroll
            for (int mt = 0; mt < 2; mt++) {
                uint32_t u01 = pk2(oacc[mt][nt][0], oacc[mt][nt][1]);
                uint32_t u23 = pk2(oacc[mt][nt][2], oacc[mt][nt][3]);
                *(uint2*)(dst + 16 * mt) = make_uint2(u01, u23);
            }
        }
    }
}

// ---------------------------------------------------------------------------
// Launch
// ---------------------------------------------------------------------------
extern "C" void kernel_launch(void* const* d_in, const int* in_sizes, int n_in,
                              void* d_out, int out_size, void* d_ws, size_t ws_size,
                              hipStream_t stream) {
    const float* x      = (const float*)d_in[0];
    const float* w_qkv  = (const float*)d_in[1];
    const float* btab   = (const float*)d_in[2];
    const float* w_proj = (const float*)d_in[3];
    const float* b_proj = (const float*)d_in[4];
    float* out = (float*)d_out;

    // workspace layout (bytes)
    char* ws = (char*)d_ws;
    const size_t off_xt   = 0;                         // 77,070,336 (reused as out_t)
    const size_t off_qkv  = 77070336;                  // 231,211,008
    const size_t off_wq   = off_qkv + 231211008;       // 884,736
    const size_t off_wp   = off_wq + 884736;           // 294,912
    const size_t off_bt   = off_wp + 294912;           // 196,608
    unsigned short* xt   = (unsigned short*)(ws + off_xt);
    unsigned short* qkvt = (unsigned short*)(ws + off_qkv);
    unsigned short* wqb  = (unsigned short*)(ws + off_wq);
    unsigned short* wpb  = (unsigned short*)(ws + off_wp);
    float*          bt   = (float*)(ws + off_bt);
    unsigned short* outt = xt;   // alias: xt dead after gemm_qkv

    cvt_f32_bf16<<<(C3 * CDIM / 4 + 255) / 256, 256, 0, stream>>>(w_qkv, wqb, C3 * CDIM / 4);
    cvt_f32_bf16<<<(CDIM * CDIM / 4 + 255) / 256, 256, 0, stream>>>(w_proj, wpb, CDIM * CDIM / 4);
    bias_pre<<<192, 256, 0, stream>>>(btab, bt);
    transpose_x<<<dim3(98, 12, 32), dim3(32, 8), 0, stream>>>(x, xt);
    gemm_qkv<<<dim3(9, 784), 256, 0, stream>>>(xt, wqb, qkvt);
    attn_mfma<<<dim3(NWIN, NHEAD), 64, 0, stream>>>(qkvt, bt, outt);
    gemm_proj<<<dim3(784, 3), 256, 0, stream>>>(wpb, outt, b_proj, out);
}